// Round 6
// baseline (37.965 us; speedup 1.0000x reference)
//
#include <hip/hip_runtime.h>

// HungarianMatcher batched cost matrix.
// B=64, Q=900, T=300, C=80. out[b][q][t] f32.
// cost = 5*cbbox + (2*ccls + 2) - 2*(inter*ca + uni^2)/(uni*ca)
//
// R6 = R2's launch shape (256 thr, QTILE=10, 5760 blocks, float4 stores;
// the only regime that ran VALUBusy ~87%) with the instruction stream cut:
//  - each 10-b128 target load shared across TWO q's (8 elems, not 4)
//  - single v_rcp per element (combined fraction), pre-scaled class table
//  - clamps dropped where provably no-op; pred area derived not stored
// R3/R4/R5's inverted long-loop structure was latency-stuck at 37-42us.

constexpr int B = 64, Q = 900, T = 300, C = 80;
constexpr int QTILE = 10;            // 900 % 10 == 0 -> 90 q-tiles, grid 5760
constexpr int BLOCK = 256;
constexpr int TG    = T / 4;         // 75 t-groups of 4
constexpr int NIT   = (QTILE / 2) * TG;  // 375 (q-pair, t-group) units
constexpr float ALPHA = 0.25f;
constexpr float EPSF  = 1e-8f;

__device__ __forceinline__ float fast_rcp(float x) {
    return __builtin_amdgcn_rcpf(x);   // v_rcp_f32, ~1 ulp
}

__global__ __launch_bounds__(BLOCK) void matcher_cost_kernel(
    const float* __restrict__ logits,   // [B,Q,C]
    const float* __restrict__ pboxes,   // [B,Q,4] cxcywh
    const int*   __restrict__ tlabels,  // [B,T]
    const float* __restrict__ tboxes,   // [B,T,4] cxcywh
    float* __restrict__ out)            // [B,Q,T]
{
    // Target SoA as float4-per-4t: cx,cy,w,h,x0,y0,x1,y1,area
    __shared__ float4 s_t[9][TG];
    __shared__ int4   s_tl[TG];
    __shared__ float  s_cls[QTILE * C];  // 2*ccls + 2
    __shared__ float4 s_pA[QTILE];       // cx,cy,w,h
    __shared__ float4 s_pB[QTILE];       // x0,y0,x1,y1

    const int bid = blockIdx.x;
    const int b   = bid / (Q / QTILE);
    const int q0  = (bid % (Q / QTILE)) * QTILE;
    const int tid = threadIdx.x;

    // ---- stage targets ----
    for (int t = tid; t < T; t += BLOCK) {
        float4 bx = *(const float4*)(tboxes + ((size_t)b * T + t) * 4);
        float x0 = bx.x - 0.5f * bx.z, y0 = bx.y - 0.5f * bx.w;
        float x1 = bx.x + 0.5f * bx.z, y1 = bx.y + 0.5f * bx.w;
        ((float*)&s_t[0][0])[t] = bx.x;
        ((float*)&s_t[1][0])[t] = bx.y;
        ((float*)&s_t[2][0])[t] = bx.z;
        ((float*)&s_t[3][0])[t] = bx.w;
        ((float*)&s_t[4][0])[t] = x0;
        ((float*)&s_t[5][0])[t] = y0;
        ((float*)&s_t[6][0])[t] = x1;
        ((float*)&s_t[7][0])[t] = y1;
        ((float*)&s_t[8][0])[t] = bx.z * bx.w;
        ((int*)&s_tl[0])[t]     = tlabels[(size_t)b * T + t];
    }

    // ---- stage pred boxes ----
    if (tid < QTILE) {
        float4 bx = *(const float4*)(pboxes + ((size_t)b * Q + q0 + tid) * 4);
        float x0 = bx.x - 0.5f * bx.z, y0 = bx.y - 0.5f * bx.w;
        float x1 = bx.x + 0.5f * bx.z, y1 = bx.y + 0.5f * bx.w;
        s_pA[tid] = bx;
        s_pB[tid] = make_float4(x0, y0, x1, y1);
    }

    // ---- focal class table, pre-scaled (2*ccls + 2) ----
    {
        const float* lg = logits + ((size_t)b * Q + q0) * C;  // 800 contiguous
        for (int i = tid; i < QTILE * C; i += BLOCK) {
            float x  = lg[i];
            float pr = fast_rcp(1.0f + __expf(-x));
            float om = 1.0f - pr;
            float pos = ALPHA * om * om * (-__logf(pr + EPSF));
            float neg = (1.0f - ALPHA) * pr * pr * (-__logf(om + EPSF));
            s_cls[i] = 2.0f * (pos - neg) + 2.0f;
        }
    }

    __syncthreads();

    // ---- main: 375 (q-pair, 4t-group) units; targets shared across 2 q ----
    float* outb = out + ((size_t)b * Q + q0) * T;
    for (unsigned it = tid; it < NIT; it += BLOCK) {
        unsigned qp = it / TG;           // 0..4 (magic-mul)
        unsigned tg = it - qp * TG;      // 0..74

        float4 tcx = s_t[0][tg], tcy = s_t[1][tg];
        float4 tw  = s_t[2][tg], th  = s_t[3][tg];
        float4 tx0 = s_t[4][tg], ty0 = s_t[5][tg];
        float4 tx1 = s_t[6][tg], ty1 = s_t[7][tg];
        float4 ta  = s_t[8][tg];
        int4   lab = s_tl[tg];

        #pragma unroll
        for (int dq = 0; dq < 2; ++dq) {
            const int ql = qp * 2 + dq;
            float4 pA = s_pA[ql];            // broadcast b128
            float4 pB = s_pB[ql];            // broadcast b128
            float  pa = pA.z * pA.w;
            const float* clsrow = s_cls + ql * C;

            float4 res;
            #pragma unroll
            for (int k = 0; k < 4; ++k) {
                float tcx_ = (&tcx.x)[k], tcy_ = (&tcy.x)[k];
                float tw_  = (&tw.x)[k],  th_  = (&th.x)[k];
                float tx0_ = (&tx0.x)[k], ty0_ = (&ty0.x)[k];
                float tx1_ = (&tx1.x)[k], ty1_ = (&ty1.x)[k];
                float ta_  = (&ta.x)[k];

                float cbbox = fabsf(pA.x - tcx_) + fabsf(pA.y - tcy_) +
                              fabsf(pA.z - tw_ ) + fabsf(pA.w - th_ );
                float cls2 = clsrow[(&lab.x)[k]];   // random 4B gather

                float iw = fmaxf(fminf(pB.z, tx1_) - fmaxf(pB.x, tx0_), 0.0f);
                float ih = fmaxf(fminf(pB.w, ty1_) - fmaxf(pB.y, ty0_), 0.0f);
                float inter = iw * ih;
                float uni   = pa + ta_ - inter;

                float cw = fmaxf(pB.z, tx1_) - fminf(pB.x, tx0_);  // >= 0
                float ch = fmaxf(pB.w, ty1_) - fminf(pB.y, ty0_);  // >= 0
                float ca = cw * ch;

                // c = 5*cbbox + cls2 - 2*(inter*ca + uni^2)/(uni*ca)
                float num = fmaf(uni, uni, inter * ca);
                float r   = fast_rcp(uni * ca);
                float c   = fmaf(5.0f, cbbox, cls2);
                c = fmaf(num, -2.0f * r, c);

                if (c != c) c = 1.0f;   // nan_to_num; |finite c| << 1e6

                (&res.x)[k] = c;
            }
            *(float4*)(outb + (size_t)ql * T + tg * 4) = res;  // coalesced 16B
        }
    }
}

extern "C" void kernel_launch(void* const* d_in, const int* in_sizes, int n_in,
                              void* d_out, int out_size, void* d_ws, size_t ws_size,
                              hipStream_t stream) {
    const float* logits  = (const float*)d_in[0];  // [B,Q,C]
    const float* pboxes  = (const float*)d_in[1];  // [B,Q,4]
    const int*   tlabels = (const int*)  d_in[2];  // [B,T]
    const float* tboxes  = (const float*)d_in[3];  // [B,T,4]
    float* out = (float*)d_out;                    // [B,Q,T]

    dim3 grid(B * (Q / QTILE));   // 5760 blocks
    dim3 block(BLOCK);
    matcher_cost_kernel<<<grid, block, 0, stream>>>(logits, pboxes, tlabels, tboxes, out);
}

// Round 7
// 34.695 us; speedup vs baseline: 1.0942x; 1.0942x over previous
//
#include <hip/hip_runtime.h>

// HungarianMatcher batched cost matrix.
// B=64, Q=900, T=300, C=80. out[b][q][t] f32.
// cost = 5*cbbox + (2*ccls + 2) - 2*(inter*ca + uni^2)/(uni*ca)
//
// R7: dual-pipe diet. LDS is ~13us of pipe time at R2's 52 B/elem, VALU
// ~8us, writes ~10.5us. Halve target-field LDS traffic by sharing each
// 10x b128 target read across TWO q's (32 B/elem total), keep every VALU
// cut (single rcp, pre-scaled class, no dead clamps, derived areas).
// QTILE=18 -> NIT=675: 96% wave-granular efficiency, grid 3200 (12.5
// blocks/CU), 18.4KB LDS -> 8 blocks/CU.

constexpr int B = 64, Q = 900, T = 300, C = 80;
constexpr int QTILE = 18;            // 900 % 18 == 0 -> 50 q-tiles, grid 3200
constexpr int BLOCK = 256;
constexpr int TG    = T / 4;         // 75 t-groups of 4
constexpr int NIT   = (QTILE / 2) * TG;  // 675 (q-pair, t-group) units
constexpr float ALPHA = 0.25f;
constexpr float EPSF  = 1e-8f;

__device__ __forceinline__ float fast_rcp(float x) {
    return __builtin_amdgcn_rcpf(x);   // v_rcp_f32, ~1 ulp
}

__global__ __launch_bounds__(BLOCK) void matcher_cost_kernel(
    const float* __restrict__ logits,   // [B,Q,C]
    const float* __restrict__ pboxes,   // [B,Q,4] cxcywh
    const int*   __restrict__ tlabels,  // [B,T]
    const float* __restrict__ tboxes,   // [B,T,4] cxcywh
    float* __restrict__ out)            // [B,Q,T]
{
    // Target SoA as float4-per-4t: cx,cy,w,h,x0,y0,x1,y1,area
    __shared__ float4 s_t[9][TG];
    __shared__ int4   s_tl[TG];
    __shared__ float  s_cls[QTILE * C];  // 2*ccls + 2
    __shared__ float4 s_pA[QTILE];       // cx,cy,w,h
    __shared__ float4 s_pB[QTILE];       // x0,y0,x1,y1

    const int bid = blockIdx.x;
    const int b   = bid / (Q / QTILE);
    const int q0  = (bid % (Q / QTILE)) * QTILE;
    const int tid = threadIdx.x;

    // ---- stage targets ----
    for (int t = tid; t < T; t += BLOCK) {
        float4 bx = *(const float4*)(tboxes + ((size_t)b * T + t) * 4);
        float x0 = bx.x - 0.5f * bx.z, y0 = bx.y - 0.5f * bx.w;
        float x1 = bx.x + 0.5f * bx.z, y1 = bx.y + 0.5f * bx.w;
        ((float*)&s_t[0][0])[t] = bx.x;
        ((float*)&s_t[1][0])[t] = bx.y;
        ((float*)&s_t[2][0])[t] = bx.z;
        ((float*)&s_t[3][0])[t] = bx.w;
        ((float*)&s_t[4][0])[t] = x0;
        ((float*)&s_t[5][0])[t] = y0;
        ((float*)&s_t[6][0])[t] = x1;
        ((float*)&s_t[7][0])[t] = y1;
        ((float*)&s_t[8][0])[t] = bx.z * bx.w;
        ((int*)&s_tl[0])[t]     = tlabels[(size_t)b * T + t];
    }

    // ---- stage pred boxes ----
    if (tid < QTILE) {
        float4 bx = *(const float4*)(pboxes + ((size_t)b * Q + q0 + tid) * 4);
        float x0 = bx.x - 0.5f * bx.z, y0 = bx.y - 0.5f * bx.w;
        float x1 = bx.x + 0.5f * bx.z, y1 = bx.y + 0.5f * bx.w;
        s_pA[tid] = bx;
        s_pB[tid] = make_float4(x0, y0, x1, y1);
    }

    // ---- focal class table, pre-scaled (2*ccls + 2) ----
    {
        const float* lg = logits + ((size_t)b * Q + q0) * C;  // 1440 contiguous
        for (int i = tid; i < QTILE * C; i += BLOCK) {
            float x  = lg[i];
            float pr = fast_rcp(1.0f + __expf(-x));
            float om = 1.0f - pr;
            float pos = ALPHA * om * om * (-__logf(pr + EPSF));
            float neg = (1.0f - ALPHA) * pr * pr * (-__logf(om + EPSF));
            s_cls[i] = 2.0f * (pos - neg) + 2.0f;
        }
    }

    __syncthreads();

    // ---- main: 675 (q-pair, 4t-group) units; targets shared across 2 q ----
    float* outb = out + ((size_t)b * Q + q0) * T;
    for (unsigned it = tid; it < NIT; it += BLOCK) {
        unsigned qp = it / TG;           // 0..8 (magic-mul)
        unsigned tg = it - qp * TG;      // 0..74

        float4 tcx = s_t[0][tg], tcy = s_t[1][tg];
        float4 tw  = s_t[2][tg], th  = s_t[3][tg];
        float4 tx0 = s_t[4][tg], ty0 = s_t[5][tg];
        float4 tx1 = s_t[6][tg], ty1 = s_t[7][tg];
        float4 ta  = s_t[8][tg];
        int4   lab = s_tl[tg];

        #pragma unroll
        for (int dq = 0; dq < 2; ++dq) {
            const int ql = qp * 2 + dq;
            float4 pA = s_pA[ql];            // 1-2 distinct addrs per wave
            float4 pB = s_pB[ql];
            float  pa = pA.z * pA.w;
            const float* clsrow = s_cls + ql * C;

            float4 res;
            #pragma unroll
            for (int k = 0; k < 4; ++k) {
                float tcx_ = (&tcx.x)[k], tcy_ = (&tcy.x)[k];
                float tw_  = (&tw.x)[k],  th_  = (&th.x)[k];
                float tx0_ = (&tx0.x)[k], ty0_ = (&ty0.x)[k];
                float tx1_ = (&tx1.x)[k], ty1_ = (&ty1.x)[k];
                float ta_  = (&ta.x)[k];

                // |a-b| pairs fold to abs input modifiers on the adds
                float cbbox = (fabsf(pA.x - tcx_) + fabsf(pA.y - tcy_)) +
                              (fabsf(pA.z - tw_ ) + fabsf(pA.w - th_ ));
                float cls2 = clsrow[(&lab.x)[k]];   // random 4B gather

                float iw = fmaxf(fminf(pB.z, tx1_) - fmaxf(pB.x, tx0_), 0.0f);
                float ih = fmaxf(fminf(pB.w, ty1_) - fmaxf(pB.y, ty0_), 0.0f);
                float inter = iw * ih;
                float uni   = (pa + ta_) - inter;

                float cw = fmaxf(pB.z, tx1_) - fminf(pB.x, tx0_);  // >= 0
                float ch = fmaxf(pB.w, ty1_) - fminf(pB.y, ty0_);  // >= 0
                float ca = cw * ch;

                // c = 5*cbbox + cls2 - 2*(inter*ca + uni^2)/(uni*ca)
                float num = fmaf(uni, uni, inter * ca);
                float r   = fast_rcp(uni * ca);
                float c   = fmaf(5.0f, cbbox, cls2);
                c = fmaf(num, -2.0f * r, c);

                if (c != c) c = 1.0f;   // nan_to_num; |finite c| << 1e6

                (&res.x)[k] = c;
            }
            *(float4*)(outb + (size_t)ql * T + tg * 4) = res;  // coalesced 16B
        }
    }
}

extern "C" void kernel_launch(void* const* d_in, const int* in_sizes, int n_in,
                              void* d_out, int out_size, void* d_ws, size_t ws_size,
                              hipStream_t stream) {
    const float* logits  = (const float*)d_in[0];  // [B,Q,C]
    const float* pboxes  = (const float*)d_in[1];  // [B,Q,4]
    const int*   tlabels = (const int*)  d_in[2];  // [B,T]
    const float* tboxes  = (const float*)d_in[3];  // [B,T,4]
    float* out = (float*)d_out;                    // [B,Q,T]

    dim3 grid(B * (Q / QTILE));   // 3200 blocks
    dim3 block(BLOCK);
    matcher_cost_kernel<<<grid, block, 0, stream>>>(logits, pboxes, tlabels, tboxes, out);
}